// Round 5
// baseline (312.190 us; speedup 1.0000x reference)
//
#include <hip/hip_runtime.h>
#include <hip/hip_bf16.h>
#include <math.h>

#define NN 13
#define SS 128
#define HH 768
#define DD 512

typedef __attribute__((ext_vector_type(8))) short bf16x8;
typedef __attribute__((ext_vector_type(4))) float f32x4;

__device__ __forceinline__ float gelu_f(float x) {
    return 0.5f * x * (1.0f + erff(x * 0.7071067811865475f));
}
__device__ __forceinline__ ushort f2b(float v) {
    __hip_bfloat16 h = __float2bfloat16(v);
    return *reinterpret_cast<ushort*>(&h);
}
__device__ __forceinline__ float b2f(ushort u) {
    __hip_bfloat16 h = *reinterpret_cast<__hip_bfloat16*>(&u);
    return __bfloat162float(h);
}

__device__ __forceinline__ int shape_hash(const int* __restrict__ active,
                                          const int* __restrict__ is_leaf, int b) {
    unsigned long long acc = 0ull, w = 1ull;
    for (int i = 0; i < NN; ++i) {
        unsigned long long p = (unsigned long long)(active[b*NN + i] * 2 + is_leaf[b*NN + i]);
        acc += p * w;
        w *= 31ull;
    }
    long long h = (long long)acc;
    if (h < 0) h = -h;
    return (int)(h % 256);
}

// ---------- pool partials: block = (unit R, s-quarter q); 192 thr, float4 lanes ----------
__global__ __launch_bounds__(192)
void pool_partial(const float* __restrict__ ls, const int* __restrict__ masks,
                  const int* __restrict__ is_leaf,
                  float* __restrict__ part, float* __restrict__ cntbuf)
{
    int idx = blockIdx.x;
    int R = idx >> 2, q = idx & 3;
    int n = R >> 6, b = R & 63;
    if (!is_leaf[b*NN + n]) return;
    const float4* src = (const float4*)(ls + (size_t)(b*NN + n) * SS * HH + (size_t)q * 32 * HH);
    const int* mk = masks + (b*NN + n) * SS + q * 32;
    int t = threadIdx.x;

    __shared__ float lsm[32];
    if (t < 32) lsm[t] = (float)mk[t];
    __syncthreads();

    float4 a = {0.f, 0.f, 0.f, 0.f};
    float cnt = 0.f;
    #pragma unroll 16
    for (int s = 0; s < 32; ++s) {
        float m = lsm[s];
        float4 v = src[s * (HH/4) + t];
        a.x += m * v.x; a.y += m * v.y; a.z += m * v.z; a.w += m * v.w;
        cnt += m;
    }
    ((float4*)(part + ((size_t)q * 832 + R) * HH))[t] = a;
    if (t == 0) cntbuf[q * 832 + R] = cnt;
}

// ---------- fused: pool combine (bx<832) + weight transpose (bx>=832) ----------
__global__ __launch_bounds__(256)
void combine_transpose(const float* __restrict__ part, const float* __restrict__ cntbuf,
                       const int* __restrict__ is_leaf, ushort* __restrict__ pooled,
                       const float* __restrict__ Wl1, const float* __restrict__ Wl2,
                       const float* __restrict__ Wm1, const float* __restrict__ Wm2,
                       ushort* __restrict__ Tl1, ushort* __restrict__ Tl2,
                       ushort* __restrict__ Tm1, ushort* __restrict__ Tm2)
{
    int bx = blockIdx.x;
    if (bx < 832) {
        int u = bx;
        int n = u >> 6, b = u & 63;
        int t = threadIdx.x;
        if (t >= 192) return;
        ushort4* dst = (ushort4*)(pooled + (size_t)u * HH);
        if (!is_leaf[b*NN + n]) {
            ushort4 z = {0, 0, 0, 0};
            dst[t] = z;
            return;
        }
        float cnt = cntbuf[u] + cntbuf[832+u] + cntbuf[1664+u] + cntbuf[2496+u];
        float inv = 1.f / fmaxf(cnt, 1.f);
        float4 s = {0.f, 0.f, 0.f, 0.f};
        #pragma unroll
        for (int q = 0; q < 4; ++q) {
            float4 v = ((const float4*)(part + ((size_t)q * 832 + u) * HH))[t];
            s.x += v.x; s.y += v.y; s.z += v.z; s.w += v.w;
        }
        ushort4 o = { f2b(s.x*inv), f2b(s.y*inv), f2b(s.z*inv), f2b(s.w*inv) };
        dst[t] = o;
        return;
    }
    // transpose part: W[K][512] f32 -> WT[512][K] bf16
    int tb = bx - 832;
    const float* W; ushort* T; int K, tile;
    if (tb < 384)       { W = Wl1; T = Tl1; K = 768;  tile = tb; }
    else if (tb < 640)  { W = Wl2; T = Tl2; K = 512;  tile = tb - 384; }
    else if (tb < 1152) { W = Wm1; T = Tm1; K = 1024; tile = tb - 640; }
    else                { W = Wm2; T = Tm2; K = 512;  tile = tb - 1152; }
    int tk = tile >> 4, tj = tile & 15;
    __shared__ float lds[32][33];
    int t = threadIdx.x;
    int r = t >> 3, c0 = (t & 7) * 4;
    const float4 v = *(const float4*)(W + (size_t)(tk*32 + r)*DD + tj*32 + c0);
    lds[r][c0+0] = v.x; lds[r][c0+1] = v.y; lds[r][c0+2] = v.z; lds[r][c0+3] = v.w;
    __syncthreads();
    ushort* dst = T + (size_t)(tj*32 + r)*K + tk*32 + c0;
    dst[0] = f2b(lds[c0+0][r]); dst[1] = f2b(lds[c0+1][r]);
    dst[2] = f2b(lds[c0+2][r]); dst[3] = f2b(lds[c0+3][r]);
}

enum { LEAF_G1 = 0, LEAF_G2 = 1, MERGE_G1 = 2, MERGE_G2 = 3, FINAL_G2 = 4 };

// Wave-K-split MFMA GEMM: block = 64 rows x 64 cols, 4 waves.
// Per 128-wide K super-step: cooperative coalesced stage of A/B 64x128 into LDS,
// wave wv consumes k-slice wv (16 indep MFMAs into full 64x64 partial acc).
// 2 syncs per super-step; global prefetch 1 step ahead. LDS tree-reduce at end.
template<int MODE, int KT>
__global__ __launch_bounds__(256)
void mfma_gemm(const ushort* __restrict__ Asrc, const ushort* __restrict__ WT,
               const float* __restrict__ bias, void* __restrict__ CoutV,
               const int* __restrict__ is_leaf, const int* __restrict__ active,
               const int* __restrict__ depth, const int* __restrict__ left,
               const int* __restrict__ right,
               const float* __restrict__ depth_emb, const float* __restrict__ shape_emb,
               const ushort* __restrict__ noderep,
               int n0, int n1, int n2)
{
    constexpr int NS = KT / 128;
    // row stride 168 ushorts: [row 0..63][slice 0..3][8-elem group 0..3]
    __shared__ __align__(16) ushort sAB[2][64*168];
    ushort* sA = sAB[0];
    ushort* sB = sAB[1];
    float* redA = (float*)sAB[0];   // 16 KB each, reused post-loop
    float* redB = (float*)sAB[1];

    const int t = threadIdx.x;
    const int lane = t & 63, wv = t >> 6;
    const int j0 = blockIdx.x * 64;
    const int by = blockIdx.y;
    const int lrow = lane & 15, lhi = lane >> 4;

    int node, lc = 0, rc = 0;
    if (MODE == LEAF_G1 || MODE == LEAF_G2) {
        node = by;
        bool anyleaf = __any(is_leaf[lane*NN + node] != 0);
        if (!anyleaf) {
            if (MODE == LEAF_G2) {           // zero-init this noderep column
                ushort* dst = (ushort*)CoutV + (size_t)(node*64)*DD;
                #pragma unroll
                for (int c = 0; c < 4; ++c) {
                    int jc = j0 + c*16 + lrow;
                    #pragma unroll
                    for (int reg = 0; reg < 4; ++reg) {
                        int rw = wv*16 + lhi*4 + reg;
                        dst[(size_t)rw*DD + jc] = 0;
                    }
                }
            }
            return;
        }
    } else {
        node = (by == 0) ? n0 : ((by == 1) ? n1 : n2);
        lc = left[node]; rc = right[node];
    }

    const int AK = (MODE == LEAF_G1) ? HH : DD;
    const int rowbase = (MODE == LEAF_G1 || MODE == LEAF_G2) ? node*64
                       : (MODE == MERGE_G1) ? 0 : by*64;

    int ur[4], ukc[4];
    #pragma unroll
    for (int u = 0; u < 4; ++u) {
        int chunk = u*256 + t;
        ur[u] = chunk >> 4;       // row 0..63
        ukc[u] = chunk & 15;      // 8-elem k-group 0..15
    }

    f32x4 acc[4][4];
    #pragma unroll
    for (int r = 0; r < 4; ++r)
        #pragma unroll
        for (int c = 0; c < 4; ++c) acc[r][c] = (f32x4){0.f,0.f,0.f,0.f};

    uint4 aR[4], bR[4];
    auto prefetch = [&](int ss) {
        #pragma unroll
        for (int u = 0; u < 4; ++u) {
            int kg = ss*128 + ukc[u]*8;
            const ushort* ap;
            if (MODE == MERGE_G1) {
                ap = (kg < DD) ? noderep + (size_t)(lc*64 + ur[u])*DD + kg
                               : noderep + (size_t)(rc*64 + ur[u])*DD + (kg - DD);
            } else {
                ap = Asrc + (size_t)(rowbase + ur[u])*AK + kg;
            }
            aR[u] = *(const uint4*)ap;
            bR[u] = *(const uint4*)(WT + (size_t)(j0 + ur[u])*KT + kg);
        }
    };
    auto commit = [&]() {
        #pragma unroll
        for (int u = 0; u < 4; ++u) {
            int off = ur[u]*168 + (ukc[u] >> 2)*40 + (ukc[u] & 3)*8;
            *(uint4*)&sA[off] = aR[u];
            *(uint4*)&sB[off] = bR[u];
        }
    };

    prefetch(0);
    for (int ss = 0; ss < NS; ++ss) {
        __syncthreads();                 // prior compute done reading LDS
        commit();
        __syncthreads();                 // staged data visible
        if (ss + 1 < NS) prefetch(ss + 1);
        bf16x8 af[4], bf[4];
        #pragma unroll
        for (int r = 0; r < 4; ++r)
            af[r] = *(const bf16x8*)&sA[(r*16 + lrow)*168 + wv*40 + lhi*8];
        #pragma unroll
        for (int c = 0; c < 4; ++c)
            bf[c] = *(const bf16x8*)&sB[(c*16 + lrow)*168 + wv*40 + lhi*8];
        #pragma unroll
        for (int r = 0; r < 4; ++r)
            #pragma unroll
            for (int c = 0; c < 4; ++c)
                acc[r][c] = __builtin_amdgcn_mfma_f32_16x16x32_bf16(af[r], bf[c], acc[r][c], 0, 0, 0);
    }

    // ---------- cross-wave reduction: waves 0/1 end with rows 0-31 / 32-63 ----------
    auto stf = [&](float* buf, int r, int c, f32x4 v) {
        *(f32x4*)&buf[((r*4 + c)*64 + lane)*4] = v;
    };
    auto ldf = [&](float* buf, int r, int c) {
        return *(const f32x4*)&buf[((r*4 + c)*64 + lane)*4];
    };
    __syncthreads();
    if (wv == 2) {
        #pragma unroll
        for (int r = 0; r < 4; ++r)
            #pragma unroll
            for (int c = 0; c < 4; ++c) stf(redA, r, c, acc[r][c]);
    } else if (wv == 3) {
        #pragma unroll
        for (int r = 0; r < 4; ++r)
            #pragma unroll
            for (int c = 0; c < 4; ++c) stf(redB, r, c, acc[r][c]);
    }
    __syncthreads();
    if (wv == 0) {
        #pragma unroll
        for (int r = 0; r < 4; ++r)
            #pragma unroll
            for (int c = 0; c < 4; ++c) { f32x4 v = ldf(redA, r, c); acc[r][c] += v; }
    } else if (wv == 1) {
        #pragma unroll
        for (int r = 0; r < 4; ++r)
            #pragma unroll
            for (int c = 0; c < 4; ++c) { f32x4 v = ldf(redB, r, c); acc[r][c] += v; }
    }
    __syncthreads();
    if (wv == 1) {
        #pragma unroll
        for (int r = 0; r < 2; ++r)
            #pragma unroll
            for (int c = 0; c < 4; ++c) stf(redA, r, c, acc[r][c]);
    } else if (wv == 0) {
        #pragma unroll
        for (int r = 2; r < 4; ++r)
            #pragma unroll
            for (int c = 0; c < 4; ++c) stf(redB, r, c, acc[r][c]);
    }
    __syncthreads();
    if (wv >= 2) return;
    const int rs = wv * 2;               // wave0 -> frags 0,1 ; wave1 -> frags 2,3
    if (wv == 0) {
        #pragma unroll
        for (int r = 0; r < 2; ++r)
            #pragma unroll
            for (int c = 0; c < 4; ++c) { f32x4 v = ldf(redA, r, c); acc[r][c] += v; }
    } else {
        #pragma unroll
        for (int r = 2; r < 4; ++r)
            #pragma unroll
            for (int c = 0; c < 4; ++c) { f32x4 v = ldf(redB, r, c); acc[r][c] += v; }
    }

    // ---------------- epilogue (waves 0,1; 2 row-frags each) ----------------
    if (MODE == LEAF_G1) {
        ushort* H = (ushort*)CoutV + (size_t)(node*64)*DD;
        #pragma unroll
        for (int rf = 0; rf < 2; ++rf)
            #pragma unroll
            for (int c = 0; c < 4; ++c) {
                int jc = j0 + c*16 + lrow;
                float bj = bias[jc];
                #pragma unroll
                for (int reg = 0; reg < 4; ++reg) {
                    int rw = (rs+rf)*16 + lhi*4 + reg;
                    H[(size_t)rw*DD + jc] = f2b(gelu_f(acc[rs+rf][c][reg] + bj));
                }
            }
    } else if (MODE == LEAF_G2) {
        int dp = depth[node];
        const float* de = depth_emb + (size_t)dp*DD;
        ushort* dst = (ushort*)CoutV + (size_t)(node*64)*DD;
        #pragma unroll
        for (int rf = 0; rf < 2; ++rf) {
            bool lf[4];
            #pragma unroll
            for (int reg = 0; reg < 4; ++reg)
                lf[reg] = is_leaf[((rs+rf)*16 + lhi*4 + reg)*NN + node] != 0;
            #pragma unroll
            for (int c = 0; c < 4; ++c) {
                int jc = j0 + c*16 + lrow;
                float bj = bias[jc] + de[jc];
                #pragma unroll
                for (int reg = 0; reg < 4; ++reg) {
                    int rw = (rs+rf)*16 + lhi*4 + reg;
                    dst[(size_t)rw*DD + jc] = f2b(lf[reg] ? (acc[rs+rf][c][reg] + bj) : 0.f);
                }
            }
        }
    } else if (MODE == MERGE_G1) {
        ushort* Mh = (ushort*)CoutV + (size_t)(by*64)*DD;
        #pragma unroll
        for (int rf = 0; rf < 2; ++rf)
            #pragma unroll
            for (int c = 0; c < 4; ++c) {
                int jc = j0 + c*16 + lrow;
                float bj = bias[jc];
                #pragma unroll
                for (int reg = 0; reg < 4; ++reg) {
                    int rw = (rs+rf)*16 + lhi*4 + reg;
                    Mh[(size_t)rw*DD + jc] = f2b(gelu_f(acc[rs+rf][c][reg] + bj));
                }
            }
    } else {
        int dp = depth[node];
        const float* de = depth_emb + (size_t)dp*DD;
        bool anyInt = __any(active[lane*NN + node] && !is_leaf[lane*NN + node]);
        if (MODE == MERGE_G2) {
            if (!anyInt) return;             // keep existing noderep column
            ushort* dst = (ushort*)CoutV + (size_t)(node*64)*DD;
            #pragma unroll
            for (int rf = 0; rf < 2; ++rf) {
                bool iv[4];
                #pragma unroll
                for (int reg = 0; reg < 4; ++reg) {
                    int rw = (rs+rf)*16 + lhi*4 + reg;
                    iv[reg] = active[rw*NN + node] && !is_leaf[rw*NN + node];
                }
                #pragma unroll
                for (int c = 0; c < 4; ++c) {
                    int jc = j0 + c*16 + lrow;
                    float bj = bias[jc] + de[jc];
                    #pragma unroll
                    for (int reg = 0; reg < 4; ++reg) {
                        int rw = (rs+rf)*16 + lhi*4 + reg;
                        dst[(size_t)rw*DD + jc] = f2b(iv[reg] ? (acc[rs+rf][c][reg] + bj) : 0.f);
                    }
                }
            }
        } else {  // FINAL_G2 -> f32 out + shape_emb
            float* out = (float*)CoutV;
            #pragma unroll
            for (int rf = 0; rf < 2; ++rf) {
                bool iv[4];
                int hh[4];
                #pragma unroll
                for (int reg = 0; reg < 4; ++reg) {
                    int rw = (rs+rf)*16 + lhi*4 + reg;
                    iv[reg] = active[rw*NN + node] && !is_leaf[rw*NN + node];
                    hh[reg] = shape_hash(active, is_leaf, rw);
                }
                #pragma unroll
                for (int c = 0; c < 4; ++c) {
                    int jc = j0 + c*16 + lrow;
                    float bj = bias[jc] + de[jc];
                    #pragma unroll
                    for (int reg = 0; reg < 4; ++reg) {
                        int rw = (rs+rf)*16 + lhi*4 + reg;
                        float base = anyInt ? (iv[reg] ? (acc[rs+rf][c][reg] + bj) : 0.f)
                                            : b2f(noderep[(size_t)(node*64 + rw)*DD + jc]);
                        out[(size_t)rw*DD + jc] = base + shape_emb[(size_t)hh[reg]*DD + jc];
                    }
                }
            }
        }
    }
}

extern "C" void kernel_launch(void* const* d_in, const int* in_sizes, int n_in,
                              void* d_out, int out_size, void* d_ws, size_t ws_size,
                              hipStream_t stream)
{
    const int*   is_leaf     = (const int*)d_in[0];
    const int*   active      = (const int*)d_in[1];
    const int*   depth       = (const int*)d_in[2];
    const int*   left        = (const int*)d_in[3];
    const int*   right       = (const int*)d_in[4];
    const float* leaf_states = (const float*)d_in[5];
    const int*   leaf_masks  = (const int*)d_in[6];
    const float* Wl1 = (const float*)d_in[7];
    const float* bl1 = (const float*)d_in[8];
    const float* Wl2 = (const float*)d_in[9];
    const float* bl2 = (const float*)d_in[10];
    const float* Wm1 = (const float*)d_in[11];
    const float* bm1 = (const float*)d_in[12];
    const float* Wm2 = (const float*)d_in[13];
    const float* bm2 = (const float*)d_in[14];
    const float* depth_emb = (const float*)d_in[15];
    const float* shape_emb = (const float*)d_in[16];
    float* out = (float*)d_out;

    // ws layout: f32 region first, then bf16 (ushort) region; all 16B-aligned
    float* part   = (float*)d_ws;                 // 4*832*768 f32
    float* cntbuf = part + 4*832*768;             // 4*832 f32
    ushort* pooled  = (ushort*)(cntbuf + 4*832);  // 832*768 bf16
    ushort* hidden  = pooled + 832*768;           // 832*512
    ushort* noderep = hidden + 832*512;           // 832*512
    ushort* mhid    = noderep + 832*512;          // 3*64*512
    ushort* Tl1 = mhid + 3*64*512;                // 512*768
    ushort* Tl2 = Tl1 + 512*768;                  // 512*512
    ushort* Tm1 = Tl2 + 512*512;                  // 512*1024
    ushort* Tm2 = Tm1 + 512*1024;                 // 512*512

    pool_partial<<<832*4, 192, 0, stream>>>(leaf_states, leaf_masks, is_leaf, part, cntbuf);
    combine_transpose<<<832 + 1408, 256, 0, stream>>>(part, cntbuf, is_leaf, pooled,
                                                      Wl1, Wl2, Wm1, Wm2, Tl1, Tl2, Tm1, Tm2);

    // leaf MLP (all nodes; no-leaf nodes short-circuit / zero-fill)
    mfma_gemm<LEAF_G1, 768><<<dim3(8, 13), 256, 0, stream>>>(
        pooled, Tl1, bl1, hidden, is_leaf, active, depth, left, right,
        depth_emb, shape_emb, noderep, 0, 0, 0);
    mfma_gemm<LEAF_G2, 512><<<dim3(8, 13), 256, 0, stream>>>(
        hidden, Tl2, bl2, noderep, is_leaf, active, depth, left, right,
        depth_emb, shape_emb, noderep, 0, 0, 0);

    // merge level 1: nodes {3,4,5}
    mfma_gemm<MERGE_G1, 1024><<<dim3(8, 3), 256, 0, stream>>>(
        nullptr, Tm1, bm1, mhid, is_leaf, active, depth, left, right,
        depth_emb, shape_emb, noderep, 3, 4, 5);
    mfma_gemm<MERGE_G2, 512><<<dim3(8, 3), 256, 0, stream>>>(
        mhid, Tm2, bm2, noderep, is_leaf, active, depth, left, right,
        depth_emb, shape_emb, noderep, 3, 4, 5);

    // merge level 2: nodes {1,2}
    mfma_gemm<MERGE_G1, 1024><<<dim3(8, 2), 256, 0, stream>>>(
        nullptr, Tm1, bm1, mhid, is_leaf, active, depth, left, right,
        depth_emb, shape_emb, noderep, 1, 2, 0);
    mfma_gemm<MERGE_G2, 512><<<dim3(8, 2), 256, 0, stream>>>(
        mhid, Tm2, bm2, noderep, is_leaf, active, depth, left, right,
        depth_emb, shape_emb, noderep, 1, 2, 0);

    // merge level 3: node {0} -> fused hash + shape_emb + f32 output
    mfma_gemm<MERGE_G1, 1024><<<dim3(8, 1), 256, 0, stream>>>(
        nullptr, Tm1, bm1, mhid, is_leaf, active, depth, left, right,
        depth_emb, shape_emb, noderep, 0, 0, 0);
    mfma_gemm<FINAL_G2, 512><<<dim3(8, 1), 256, 0, stream>>>(
        mhid, Tm2, bm2, out, is_leaf, active, depth, left, right,
        depth_emb, shape_emb, noderep, 0, 0, 0);
}

// Round 6
// 184.198 us; speedup vs baseline: 1.6949x; 1.6949x over previous
//
#include <hip/hip_runtime.h>
#include <hip/hip_bf16.h>
#include <math.h>

#define NN 13
#define SS 128
#define HH 768
#define DD 512

typedef __attribute__((ext_vector_type(8))) short bf16x8;
typedef __attribute__((ext_vector_type(4))) float f32x4;

__device__ __forceinline__ float gelu_f(float x) {
    return 0.5f * x * (1.0f + erff(x * 0.7071067811865475f));
}
__device__ __forceinline__ ushort f2b(float v) {
    __hip_bfloat16 h = __float2bfloat16(v);
    return *reinterpret_cast<ushort*>(&h);
}
__device__ __forceinline__ float b2f(ushort u) {
    __hip_bfloat16 h = *reinterpret_cast<__hip_bfloat16*>(&u);
    return __bfloat162float(h);
}

__device__ __forceinline__ int shape_hash(const int* __restrict__ active,
                                          const int* __restrict__ is_leaf, int b) {
    unsigned long long acc = 0ull, w = 1ull;
    for (int i = 0; i < NN; ++i) {
        unsigned long long p = (unsigned long long)(active[b*NN + i] * 2 + is_leaf[b*NN + i]);
        acc += p * w;
        w *= 31ull;
    }
    long long h = (long long)acc;
    if (h < 0) h = -h;
    return (int)(h % 256);
}

// ---------- pool partials: block = (unit R, s-quarter q); 192 thr, float4 lanes ----------
__global__ __launch_bounds__(192)
void pool_partial(const float* __restrict__ ls, const int* __restrict__ masks,
                  const int* __restrict__ is_leaf,
                  float* __restrict__ part, float* __restrict__ cntbuf)
{
    int idx = blockIdx.x;
    int R = idx >> 2, q = idx & 3;
    int n = R >> 6, b = R & 63;
    if (!is_leaf[b*NN + n]) return;
    const float4* src = (const float4*)(ls + (size_t)(b*NN + n) * SS * HH + (size_t)q * 32 * HH);
    const int* mk = masks + (b*NN + n) * SS + q * 32;
    int t = threadIdx.x;

    __shared__ float lsm[32];
    if (t < 32) lsm[t] = (float)mk[t];
    __syncthreads();

    float4 a = {0.f, 0.f, 0.f, 0.f};
    float cnt = 0.f;
    #pragma unroll 16
    for (int s = 0; s < 32; ++s) {
        float m = lsm[s];
        float4 v = src[s * (HH/4) + t];
        a.x += m * v.x; a.y += m * v.y; a.z += m * v.z; a.w += m * v.w;
        cnt += m;
    }
    ((float4*)(part + ((size_t)q * 832 + R) * HH))[t] = a;
    if (t == 0) cntbuf[q * 832 + R] = cnt;
}

// ---------- fused: pool combine (bx<832) + weight transpose (bx>=832) ----------
__global__ __launch_bounds__(256)
void combine_transpose(const float* __restrict__ part, const float* __restrict__ cntbuf,
                       const int* __restrict__ is_leaf, ushort* __restrict__ pooled,
                       const float* __restrict__ Wl1, const float* __restrict__ Wl2,
                       const float* __restrict__ Wm1, const float* __restrict__ Wm2,
                       ushort* __restrict__ Tl1, ushort* __restrict__ Tl2,
                       ushort* __restrict__ Tm1, ushort* __restrict__ Tm2)
{
    int bx = blockIdx.x;
    if (bx < 832) {
        int u = bx;
        int n = u >> 6, b = u & 63;
        int t = threadIdx.x;
        if (t >= 192) return;
        ushort4* dst = (ushort4*)(pooled + (size_t)u * HH);
        if (!is_leaf[b*NN + n]) {
            ushort4 z = {0, 0, 0, 0};
            dst[t] = z;
            return;
        }
        float cnt = cntbuf[u] + cntbuf[832+u] + cntbuf[1664+u] + cntbuf[2496+u];
        float inv = 1.f / fmaxf(cnt, 1.f);
        float4 s = {0.f, 0.f, 0.f, 0.f};
        #pragma unroll
        for (int q = 0; q < 4; ++q) {
            float4 v = ((const float4*)(part + ((size_t)q * 832 + u) * HH))[t];
            s.x += v.x; s.y += v.y; s.z += v.z; s.w += v.w;
        }
        ushort4 o = { f2b(s.x*inv), f2b(s.y*inv), f2b(s.z*inv), f2b(s.w*inv) };
        dst[t] = o;
        return;
    }
    // transpose part: W[K][512] f32 -> WT[512][K] bf16
    int tb = bx - 832;
    const float* W; ushort* T; int K, tile;
    if (tb < 384)       { W = Wl1; T = Tl1; K = 768;  tile = tb; }
    else if (tb < 640)  { W = Wl2; T = Tl2; K = 512;  tile = tb - 384; }
    else if (tb < 1152) { W = Wm1; T = Tm1; K = 1024; tile = tb - 640; }
    else                { W = Wm2; T = Tm2; K = 512;  tile = tb - 1152; }
    int tk = tile >> 4, tj = tile & 15;
    __shared__ float lds[32][33];
    int t = threadIdx.x;
    int r = t >> 3, c0 = (t & 7) * 4;
    const float4 v = *(const float4*)(W + (size_t)(tk*32 + r)*DD + tj*32 + c0);
    lds[r][c0+0] = v.x; lds[r][c0+1] = v.y; lds[r][c0+2] = v.z; lds[r][c0+3] = v.w;
    __syncthreads();
    ushort* dst = T + (size_t)(tj*32 + r)*K + tk*32 + c0;
    dst[0] = f2b(lds[c0+0][r]); dst[1] = f2b(lds[c0+1][r]);
    dst[2] = f2b(lds[c0+2][r]); dst[3] = f2b(lds[c0+3][r]);
}

enum { LEAF_G1 = 0, LEAF_G2 = 1, MERGE_G1 = 2, MERGE_G2 = 3, FINAL_G2 = 4 };

// MFMA GEMM (round-3 structure, BK=64): block = 64 rows x 64 cols; 4 waves;
// two 32-k chunks staged per barrier (same per-chunk LDS layout as round-3),
// double-buffered, ONE __syncthreads per super-step, 8 MFMAs per wave per step.
template<int MODE, int KT>
__global__ __launch_bounds__(256)
void mfma_gemm(const ushort* __restrict__ Asrc, const ushort* __restrict__ WT,
               const float* __restrict__ bias, void* __restrict__ CoutV,
               const int* __restrict__ is_leaf, const int* __restrict__ active,
               const int* __restrict__ depth, const int* __restrict__ left,
               const int* __restrict__ right,
               const float* __restrict__ depth_emb, const float* __restrict__ shape_emb,
               const ushort* __restrict__ noderep,
               int n0, int n1, int n2)
{
    constexpr int NS = KT / 64;
    __shared__ ushort a_lds[2][2][64*40];
    __shared__ ushort b_lds[2][2][64*40];

    const int t = threadIdx.x;
    const int lane = t & 63, wv = t >> 6;
    const int j0 = blockIdx.x * 64;
    const int by = blockIdx.y;
    const int lrow = lane & 15, lhi = lane >> 4;

    int node, lc = 0, rc = 0;
    if (MODE == LEAF_G1 || MODE == LEAF_G2) {
        node = by;
        bool anyleaf = __any(is_leaf[lane*NN + node] != 0);
        if (!anyleaf) {
            if (MODE == LEAF_G2) {           // zero-init this noderep column
                ushort* dst = (ushort*)CoutV + (size_t)(node*64)*DD;
                #pragma unroll
                for (int c = 0; c < 4; ++c) {
                    int jc = j0 + c*16 + lrow;
                    #pragma unroll
                    for (int reg = 0; reg < 4; ++reg) {
                        int rw = wv*16 + lhi*4 + reg;
                        dst[(size_t)rw*DD + jc] = 0;
                    }
                }
            }
            return;
        }
    } else {
        node = (by == 0) ? n0 : ((by == 1) ? n1 : n2);
        lc = left[node]; rc = right[node];
    }

    const int AK = (MODE == LEAF_G1) ? HH : DD;
    const int rowbase = (MODE == LEAF_G1 || MODE == LEAF_G2) ? node*64
                       : (MODE == MERGE_G1) ? 0 : by*64;

    const int sr = t >> 2, skg = t & 3;
    f32x4 acc[4];
    #pragma unroll
    for (int c = 0; c < 4; ++c) acc[c] = (f32x4){0.f, 0.f, 0.f, 0.f};

    uint4 aReg[2], bReg[2];
    auto loadAB = [&](int ss) {
        #pragma unroll
        for (int ch = 0; ch < 2; ++ch) {
            int k0 = ss*64 + ch*32 + skg*8;
            const ushort* ap;
            if (MODE == MERGE_G1) {
                ap = (k0 < DD) ? noderep + (size_t)(lc*64 + sr)*DD + k0
                               : noderep + (size_t)(rc*64 + sr)*DD + (k0 - DD);
            } else {
                ap = Asrc + (size_t)(rowbase + sr)*AK + k0;
            }
            aReg[ch] = *(const uint4*)ap;
            bReg[ch] = *(const uint4*)(WT + (size_t)(j0 + sr)*KT + k0);
        }
    };
    auto storeAB = [&](int buf) {
        #pragma unroll
        for (int ch = 0; ch < 2; ++ch) {
            *(uint4*)&a_lds[buf][ch][sr*40 + skg*8] = aReg[ch];
            *(uint4*)&b_lds[buf][ch][sr*40 + skg*8] = bReg[ch];
        }
    };

    loadAB(0);
    storeAB(0);
    __syncthreads();

    for (int ss = 0; ss < NS; ++ss) {
        if (ss + 1 < NS) loadAB(ss + 1);
        const int buf = ss & 1;
        #pragma unroll
        for (int ch = 0; ch < 2; ++ch) {
            bf16x8 af = *(const bf16x8*)&a_lds[buf][ch][(wv*16 + lrow)*40 + lhi*8];
            #pragma unroll
            for (int c = 0; c < 4; ++c) {
                bf16x8 bfr = *(const bf16x8*)&b_lds[buf][ch][(c*16 + lrow)*40 + lhi*8];
                acc[c] = __builtin_amdgcn_mfma_f32_16x16x32_bf16(af, bfr, acc[c], 0, 0, 0);
            }
        }
        if (ss + 1 < NS) storeAB(buf ^ 1);
        __syncthreads();
    }

    // ---------------- epilogue ----------------
    if (MODE == LEAF_G1) {
        ushort* H = (ushort*)CoutV + (size_t)(node*64)*DD;
        #pragma unroll
        for (int c = 0; c < 4; ++c) {
            int jc = j0 + c*16 + lrow;
            float bj = bias[jc];
            #pragma unroll
            for (int reg = 0; reg < 4; ++reg) {
                int rw = wv*16 + lhi*4 + reg;
                H[(size_t)rw*DD + jc] = f2b(gelu_f(acc[c][reg] + bj));
            }
        }
    } else if (MODE == LEAF_G2) {
        int dp = depth[node];
        const float* de = depth_emb + (size_t)dp*DD;
        bool lf[4];
        #pragma unroll
        for (int reg = 0; reg < 4; ++reg)
            lf[reg] = is_leaf[(wv*16 + lhi*4 + reg)*NN + node] != 0;
        ushort* dst = (ushort*)CoutV + (size_t)(node*64)*DD;
        #pragma unroll
        for (int c = 0; c < 4; ++c) {
            int jc = j0 + c*16 + lrow;
            float bj = bias[jc] + de[jc];
            #pragma unroll
            for (int reg = 0; reg < 4; ++reg) {
                int rw = wv*16 + lhi*4 + reg;
                dst[(size_t)rw*DD + jc] = f2b(lf[reg] ? (acc[c][reg] + bj) : 0.f);
            }
        }
    } else if (MODE == MERGE_G1) {
        ushort* Mh = (ushort*)CoutV + (size_t)(by*64)*DD;
        #pragma unroll
        for (int c = 0; c < 4; ++c) {
            int jc = j0 + c*16 + lrow;
            float bj = bias[jc];
            #pragma unroll
            for (int reg = 0; reg < 4; ++reg) {
                int rw = wv*16 + lhi*4 + reg;
                Mh[(size_t)rw*DD + jc] = f2b(gelu_f(acc[c][reg] + bj));
            }
        }
    } else {
        int dp = depth[node];
        const float* de = depth_emb + (size_t)dp*DD;
        bool anyInt = __any(active[lane*NN + node] && !is_leaf[lane*NN + node]);
        bool iv[4];
        #pragma unroll
        for (int reg = 0; reg < 4; ++reg) {
            int rw = wv*16 + lhi*4 + reg;
            iv[reg] = active[rw*NN + node] && !is_leaf[rw*NN + node];
        }
        if (MODE == MERGE_G2) {
            if (!anyInt) return;             // keep existing noderep column
            ushort* dst = (ushort*)CoutV + (size_t)(node*64)*DD;
            #pragma unroll
            for (int c = 0; c < 4; ++c) {
                int jc = j0 + c*16 + lrow;
                float bj = bias[jc] + de[jc];
                #pragma unroll
                for (int reg = 0; reg < 4; ++reg) {
                    int rw = wv*16 + lhi*4 + reg;
                    dst[(size_t)rw*DD + jc] = f2b(iv[reg] ? (acc[c][reg] + bj) : 0.f);
                }
            }
        } else {  // FINAL_G2 -> f32 out + shape_emb
            float* out = (float*)CoutV;
            int hh[4];
            #pragma unroll
            for (int reg = 0; reg < 4; ++reg)
                hh[reg] = shape_hash(active, is_leaf, wv*16 + lhi*4 + reg);
            #pragma unroll
            for (int c = 0; c < 4; ++c) {
                int jc = j0 + c*16 + lrow;
                float bj = bias[jc] + de[jc];
                #pragma unroll
                for (int reg = 0; reg < 4; ++reg) {
                    int rw = wv*16 + lhi*4 + reg;
                    float base = anyInt ? (iv[reg] ? (acc[c][reg] + bj) : 0.f)
                                        : b2f(noderep[(size_t)(node*64 + rw)*DD + jc]);
                    out[(size_t)rw*DD + jc] = base + shape_emb[(size_t)hh[reg]*DD + jc];
                }
            }
        }
    }
}

extern "C" void kernel_launch(void* const* d_in, const int* in_sizes, int n_in,
                              void* d_out, int out_size, void* d_ws, size_t ws_size,
                              hipStream_t stream)
{
    const int*   is_leaf     = (const int*)d_in[0];
    const int*   active      = (const int*)d_in[1];
    const int*   depth       = (const int*)d_in[2];
    const int*   left        = (const int*)d_in[3];
    const int*   right       = (const int*)d_in[4];
    const float* leaf_states = (const float*)d_in[5];
    const int*   leaf_masks  = (const int*)d_in[6];
    const float* Wl1 = (const float*)d_in[7];
    const float* bl1 = (const float*)d_in[8];
    const float* Wl2 = (const float*)d_in[9];
    const float* bl2 = (const float*)d_in[10];
    const float* Wm1 = (const float*)d_in[11];
    const float* bm1 = (const float*)d_in[12];
    const float* Wm2 = (const float*)d_in[13];
    const float* bm2 = (const float*)d_in[14];
    const float* depth_emb = (const float*)d_in[15];
    const float* shape_emb = (const float*)d_in[16];
    float* out = (float*)d_out;

    // ws layout: f32 region first, then bf16 (ushort) region; all 16B-aligned
    float* part   = (float*)d_ws;                 // 4*832*768 f32
    float* cntbuf = part + 4*832*768;             // 4*832 f32
    ushort* pooled  = (ushort*)(cntbuf + 4*832);  // 832*768 bf16
    ushort* hidden  = pooled + 832*768;           // 832*512
    ushort* noderep = hidden + 832*512;           // 832*512
    ushort* mhid    = noderep + 832*512;          // 3*64*512
    ushort* Tl1 = mhid + 3*64*512;                // 512*768
    ushort* Tl2 = Tl1 + 512*768;                  // 512*512
    ushort* Tm1 = Tl2 + 512*512;                  // 512*1024
    ushort* Tm2 = Tm1 + 512*1024;                 // 512*512

    pool_partial<<<832*4, 192, 0, stream>>>(leaf_states, leaf_masks, is_leaf, part, cntbuf);
    combine_transpose<<<832 + 1408, 256, 0, stream>>>(part, cntbuf, is_leaf, pooled,
                                                      Wl1, Wl2, Wm1, Wm2, Tl1, Tl2, Tm1, Tm2);

    // leaf MLP (all nodes; no-leaf nodes short-circuit / zero-fill)
    mfma_gemm<LEAF_G1, 768><<<dim3(8, 13), 256, 0, stream>>>(
        pooled, Tl1, bl1, hidden, is_leaf, active, depth, left, right,
        depth_emb, shape_emb, noderep, 0, 0, 0);
    mfma_gemm<LEAF_G2, 512><<<dim3(8, 13), 256, 0, stream>>>(
        hidden, Tl2, bl2, noderep, is_leaf, active, depth, left, right,
        depth_emb, shape_emb, noderep, 0, 0, 0);

    // merge level 1: nodes {3,4,5}
    mfma_gemm<MERGE_G1, 1024><<<dim3(8, 3), 256, 0, stream>>>(
        nullptr, Tm1, bm1, mhid, is_leaf, active, depth, left, right,
        depth_emb, shape_emb, noderep, 3, 4, 5);
    mfma_gemm<MERGE_G2, 512><<<dim3(8, 3), 256, 0, stream>>>(
        mhid, Tm2, bm2, noderep, is_leaf, active, depth, left, right,
        depth_emb, shape_emb, noderep, 3, 4, 5);

    // merge level 2: nodes {1,2}
    mfma_gemm<MERGE_G1, 1024><<<dim3(8, 2), 256, 0, stream>>>(
        nullptr, Tm1, bm1, mhid, is_leaf, active, depth, left, right,
        depth_emb, shape_emb, noderep, 1, 2, 0);
    mfma_gemm<MERGE_G2, 512><<<dim3(8, 2), 256, 0, stream>>>(
        mhid, Tm2, bm2, noderep, is_leaf, active, depth, left, right,
        depth_emb, shape_emb, noderep, 1, 2, 0);

    // merge level 3: node {0} -> fused hash + shape_emb + f32 output
    mfma_gemm<MERGE_G1, 1024><<<dim3(8, 1), 256, 0, stream>>>(
        nullptr, Tm1, bm1, mhid, is_leaf, active, depth, left, right,
        depth_emb, shape_emb, noderep, 0, 0, 0);
    mfma_gemm<FINAL_G2, 512><<<dim3(8, 1), 256, 0, stream>>>(
        mhid, Tm2, bm2, out, is_leaf, active, depth, left, right,
        depth_emb, shape_emb, noderep, 0, 0, 0);
}

// Round 7
// 102.744 us; speedup vs baseline: 3.0385x; 1.7928x over previous
//
#include <hip/hip_runtime.h>
#include <hip/hip_bf16.h>
#include <math.h>

#define NN 13
#define SS 128
#define HH 768
#define DD 512

typedef __attribute__((ext_vector_type(8))) short bf16x8;
typedef __attribute__((ext_vector_type(4))) float f32x4;

__device__ __forceinline__ float gelu_f(float x) {
    return 0.5f * x * (1.0f + erff(x * 0.7071067811865475f));
}
__device__ __forceinline__ ushort f2b(float v) {
    __hip_bfloat16 h = __float2bfloat16(v);
    return *reinterpret_cast<ushort*>(&h);
}
__device__ __forceinline__ float b2f(ushort u) {
    __hip_bfloat16 h = *reinterpret_cast<__hip_bfloat16*>(&u);
    return __bfloat162float(h);
}

__device__ __forceinline__ int shape_hash(const int* __restrict__ active,
                                          const int* __restrict__ is_leaf, int b) {
    unsigned long long acc = 0ull, w = 1ull;
    for (int i = 0; i < NN; ++i) {
        unsigned long long p = (unsigned long long)(active[b*NN + i] * 2 + is_leaf[b*NN + i]);
        acc += p * w;
        w *= 31ull;
    }
    long long h = (long long)acc;
    if (h < 0) h = -h;
    return (int)(h % 256);
}

// ---------- pool partials: block = (unit R, s-quarter q); 192 thr, float4 lanes ----------
__global__ __launch_bounds__(192)
void pool_partial(const float* __restrict__ ls, const int* __restrict__ masks,
                  const int* __restrict__ is_leaf,
                  float* __restrict__ part, float* __restrict__ cntbuf)
{
    int idx = blockIdx.x;
    int R = idx >> 2, q = idx & 3;
    int n = R >> 6, b = R & 63;
    if (!is_leaf[b*NN + n]) return;
    const float4* src = (const float4*)(ls + (size_t)(b*NN + n) * SS * HH + (size_t)q * 32 * HH);
    const int* mk = masks + (b*NN + n) * SS + q * 32;
    int t = threadIdx.x;

    __shared__ float lsm[32];
    if (t < 32) lsm[t] = (float)mk[t];
    __syncthreads();

    float4 a = {0.f, 0.f, 0.f, 0.f};
    float cnt = 0.f;
    #pragma unroll 16
    for (int s = 0; s < 32; ++s) {
        float m = lsm[s];
        float4 v = src[s * (HH/4) + t];
        a.x += m * v.x; a.y += m * v.y; a.z += m * v.z; a.w += m * v.w;
        cnt += m;
    }
    ((float4*)(part + ((size_t)q * 832 + R) * HH))[t] = a;
    if (t == 0) cntbuf[q * 832 + R] = cnt;
}

// ---------- fused: pool combine (bx<832) + weight transpose (bx>=832) ----------
__global__ __launch_bounds__(256)
void combine_transpose(const float* __restrict__ part, const float* __restrict__ cntbuf,
                       const int* __restrict__ is_leaf, ushort* __restrict__ pooled,
                       const float* __restrict__ Wl1, const float* __restrict__ Wl2,
                       const float* __restrict__ Wm1, const float* __restrict__ Wm2,
                       ushort* __restrict__ Tl1, ushort* __restrict__ Tl2,
                       ushort* __restrict__ Tm1, ushort* __restrict__ Tm2)
{
    int bx = blockIdx.x;
    if (bx < 832) {
        int u = bx;
        int n = u >> 6, b = u & 63;
        int t = threadIdx.x;
        if (t >= 192) return;
        ushort4* dst = (ushort4*)(pooled + (size_t)u * HH);
        if (!is_leaf[b*NN + n]) {
            ushort4 z = {0, 0, 0, 0};
            dst[t] = z;
            return;
        }
        float cnt = cntbuf[u] + cntbuf[832+u] + cntbuf[1664+u] + cntbuf[2496+u];
        float inv = 1.f / fmaxf(cnt, 1.f);
        float4 s = {0.f, 0.f, 0.f, 0.f};
        #pragma unroll
        for (int q = 0; q < 4; ++q) {
            float4 v = ((const float4*)(part + ((size_t)q * 832 + u) * HH))[t];
            s.x += v.x; s.y += v.y; s.z += v.z; s.w += v.w;
        }
        ushort4 o = { f2b(s.x*inv), f2b(s.y*inv), f2b(s.z*inv), f2b(s.w*inv) };
        dst[t] = o;
        return;
    }
    // transpose part: W[K][512] f32 -> WT[512][K] bf16
    int tb = bx - 832;
    const float* W; ushort* T; int K, tile;
    if (tb < 384)       { W = Wl1; T = Tl1; K = 768;  tile = tb; }
    else if (tb < 640)  { W = Wl2; T = Tl2; K = 512;  tile = tb - 384; }
    else if (tb < 1152) { W = Wm1; T = Tm1; K = 1024; tile = tb - 640; }
    else                { W = Wm2; T = Tm2; K = 512;  tile = tb - 1152; }
    int tk = tile >> 4, tj = tile & 15;
    __shared__ float lds[32][33];
    int t = threadIdx.x;
    int r = t >> 3, c0 = (t & 7) * 4;
    const float4 v = *(const float4*)(W + (size_t)(tk*32 + r)*DD + tj*32 + c0);
    lds[r][c0+0] = v.x; lds[r][c0+1] = v.y; lds[r][c0+2] = v.z; lds[r][c0+3] = v.w;
    __syncthreads();
    ushort* dst = T + (size_t)(tj*32 + r)*K + tk*32 + c0;
    dst[0] = f2b(lds[c0+0][r]); dst[1] = f2b(lds[c0+1][r]);
    dst[2] = f2b(lds[c0+2][r]); dst[3] = f2b(lds[c0+3][r]);
}

enum { LEAF_G1 = 0, LEAF_G2 = 1, MERGE_G1 = 2, MERGE_G2 = 3, FINAL_G2 = 4 };

// MFMA GEMM: round-3 structure (BK=32, double-buffered LDS, 1 sync/iter) with a
// 2-deep prefetch pipeline: two NAMED register sets (compile-time slots), loop
// unrolled x2 so the global load consumed by each LDS store was issued one full
// iteration earlier (hides L2 latency instead of exposing it at the store).
template<int MODE, int KT>
__global__ __launch_bounds__(256)
void mfma_gemm(const ushort* __restrict__ Asrc, const ushort* __restrict__ WT,
               const float* __restrict__ bias, void* __restrict__ CoutV,
               const int* __restrict__ is_leaf, const int* __restrict__ active,
               const int* __restrict__ depth, const int* __restrict__ left,
               const int* __restrict__ right,
               const float* __restrict__ depth_emb, const float* __restrict__ shape_emb,
               const ushort* __restrict__ noderep,
               int n0, int n1, int n2)
{
    constexpr int NITER = KT / 32;          // 16, 24, or 32 (always even)
    __shared__ ushort a_lds[2][64*40];
    __shared__ ushort b_lds[2][64*40];

    const int t = threadIdx.x;
    const int lane = t & 63, wv = t >> 6;
    const int j0 = blockIdx.x * 64;
    const int by = blockIdx.y;
    const int lrow = lane & 15, lhi = lane >> 4;

    int node, lc = 0, rc = 0;
    if (MODE == LEAF_G1 || MODE == LEAF_G2) {
        node = by;
        bool anyleaf = __any(is_leaf[lane*NN + node] != 0);
        if (!anyleaf) {
            if (MODE == LEAF_G2) {           // zero-init this noderep column
                ushort* dst = (ushort*)CoutV + (size_t)(node*64)*DD;
                #pragma unroll
                for (int c = 0; c < 4; ++c) {
                    int jc = j0 + c*16 + lrow;
                    #pragma unroll
                    for (int reg = 0; reg < 4; ++reg) {
                        int rw = wv*16 + lhi*4 + reg;
                        dst[(size_t)rw*DD + jc] = 0;
                    }
                }
            }
            return;
        }
    } else {
        node = (by == 0) ? n0 : ((by == 1) ? n1 : n2);
        lc = left[node]; rc = right[node];
    }

    const int AK = (MODE == LEAF_G1) ? HH : DD;
    const int rowbase = (MODE == LEAF_G1 || MODE == LEAF_G2) ? node*64
                       : (MODE == MERGE_G1) ? 0 : by*64;

    const int sr = t >> 2, skg = t & 3;
    f32x4 acc[4];
    #pragma unroll
    for (int c = 0; c < 4; ++c) acc[c] = (f32x4){0.f, 0.f, 0.f, 0.f};

    auto addrA = [&](int kt) -> const ushort* {
        int k0 = kt*32 + skg*8;
        if (MODE == MERGE_G1) {
            return (k0 < DD) ? noderep + (size_t)(lc*64 + sr)*DD + k0
                             : noderep + (size_t)(rc*64 + sr)*DD + (k0 - DD);
        }
        return Asrc + (size_t)(rowbase + sr)*AK + k0;
    };
    auto addrB = [&](int kt) -> const ushort* {
        return WT + (size_t)(j0 + sr)*KT + kt*32 + skg*8;
    };

    uint4 aR0, bR0, aR1, bR1;                        // two named prefetch sets
    auto load0 = [&](int kt) { aR0 = *(const uint4*)addrA(kt); bR0 = *(const uint4*)addrB(kt); };
    auto load1 = [&](int kt) { aR1 = *(const uint4*)addrA(kt); bR1 = *(const uint4*)addrB(kt); };
    auto store0 = [&](int buf) {
        *(uint4*)&a_lds[buf][sr*40 + skg*8] = aR0;
        *(uint4*)&b_lds[buf][sr*40 + skg*8] = bR0;
    };
    auto store1 = [&](int buf) {
        *(uint4*)&a_lds[buf][sr*40 + skg*8] = aR1;
        *(uint4*)&b_lds[buf][sr*40 + skg*8] = bR1;
    };
    auto computeOn = [&](const ushort* aL, const ushort* bL) {
        bf16x8 af = *(const bf16x8*)&aL[(wv*16 + lrow)*40 + lhi*8];
        #pragma unroll
        for (int c = 0; c < 4; ++c) {
            bf16x8 bfr = *(const bf16x8*)&bL[(c*16 + lrow)*40 + lhi*8];
            acc[c] = __builtin_amdgcn_mfma_f32_16x16x32_bf16(af, bfr, acc[c], 0, 0, 0);
        }
    };

    // prologue: kt0 -> buf0 (latency exposed once); prefetch kt1 -> set1
    load0(0);
    store0(0);
    if (NITER > 1) load1(1);
    __syncthreads();

    for (int kt = 0; kt < NITER; kt += 2) {
        // even half: compute buf0 (kt), prefetch kt+2 -> set0, stage kt+1 -> buf1
        computeOn(a_lds[0], b_lds[0]);
        if (kt + 2 < NITER) load0(kt + 2);
        store1(1);
        __syncthreads();
        // odd half: compute buf1 (kt+1), prefetch kt+3 -> set1, stage kt+2 -> buf0
        computeOn(a_lds[1], b_lds[1]);
        if (kt + 3 < NITER) load1(kt + 3);
        if (kt + 2 < NITER) store0(0);
        __syncthreads();
    }

    // ---------------- epilogue ----------------
    if (MODE == LEAF_G1) {
        ushort* H = (ushort*)CoutV + (size_t)(node*64)*DD;
        #pragma unroll
        for (int c = 0; c < 4; ++c) {
            int jc = j0 + c*16 + lrow;
            float bj = bias[jc];
            #pragma unroll
            for (int reg = 0; reg < 4; ++reg) {
                int rw = wv*16 + lhi*4 + reg;
                H[(size_t)rw*DD + jc] = f2b(gelu_f(acc[c][reg] + bj));
            }
        }
    } else if (MODE == LEAF_G2) {
        int dp = depth[node];
        const float* de = depth_emb + (size_t)dp*DD;
        bool lf[4];
        #pragma unroll
        for (int reg = 0; reg < 4; ++reg)
            lf[reg] = is_leaf[(wv*16 + lhi*4 + reg)*NN + node] != 0;
        ushort* dst = (ushort*)CoutV + (size_t)(node*64)*DD;
        #pragma unroll
        for (int c = 0; c < 4; ++c) {
            int jc = j0 + c*16 + lrow;
            float bj = bias[jc] + de[jc];
            #pragma unroll
            for (int reg = 0; reg < 4; ++reg) {
                int rw = wv*16 + lhi*4 + reg;
                dst[(size_t)rw*DD + jc] = f2b(lf[reg] ? (acc[c][reg] + bj) : 0.f);
            }
        }
    } else if (MODE == MERGE_G1) {
        ushort* Mh = (ushort*)CoutV + (size_t)(by*64)*DD;
        #pragma unroll
        for (int c = 0; c < 4; ++c) {
            int jc = j0 + c*16 + lrow;
            float bj = bias[jc];
            #pragma unroll
            for (int reg = 0; reg < 4; ++reg) {
                int rw = wv*16 + lhi*4 + reg;
                Mh[(size_t)rw*DD + jc] = f2b(gelu_f(acc[c][reg] + bj));
            }
        }
    } else {
        int dp = depth[node];
        const float* de = depth_emb + (size_t)dp*DD;
        bool anyInt = __any(active[lane*NN + node] && !is_leaf[lane*NN + node]);
        bool iv[4];
        #pragma unroll
        for (int reg = 0; reg < 4; ++reg) {
            int rw = wv*16 + lhi*4 + reg;
            iv[reg] = active[rw*NN + node] && !is_leaf[rw*NN + node];
        }
        if (MODE == MERGE_G2) {
            if (!anyInt) return;             // keep existing noderep column
            ushort* dst = (ushort*)CoutV + (size_t)(node*64)*DD;
            #pragma unroll
            for (int c = 0; c < 4; ++c) {
                int jc = j0 + c*16 + lrow;
                float bj = bias[jc] + de[jc];
                #pragma unroll
                for (int reg = 0; reg < 4; ++reg) {
                    int rw = wv*16 + lhi*4 + reg;
                    dst[(size_t)rw*DD + jc] = f2b(iv[reg] ? (acc[c][reg] + bj) : 0.f);
                }
            }
        } else {  // FINAL_G2 -> f32 out + shape_emb
            float* out = (float*)CoutV;
            int hh[4];
            #pragma unroll
            for (int reg = 0; reg < 4; ++reg)
                hh[reg] = shape_hash(active, is_leaf, wv*16 + lhi*4 + reg);
            #pragma unroll
            for (int c = 0; c < 4; ++c) {
                int jc = j0 + c*16 + lrow;
                float bj = bias[jc] + de[jc];
                #pragma unroll
                for (int reg = 0; reg < 4; ++reg) {
                    int rw = wv*16 + lhi*4 + reg;
                    float base = anyInt ? (iv[reg] ? (acc[c][reg] + bj) : 0.f)
                                        : b2f(noderep[(size_t)(node*64 + rw)*DD + jc]);
                    out[(size_t)rw*DD + jc] = base + shape_emb[(size_t)hh[reg]*DD + jc];
                }
            }
        }
    }
}

extern "C" void kernel_launch(void* const* d_in, const int* in_sizes, int n_in,
                              void* d_out, int out_size, void* d_ws, size_t ws_size,
                              hipStream_t stream)
{
    const int*   is_leaf     = (const int*)d_in[0];
    const int*   active      = (const int*)d_in[1];
    const int*   depth       = (const int*)d_in[2];
    const int*   left        = (const int*)d_in[3];
    const int*   right       = (const int*)d_in[4];
    const float* leaf_states = (const float*)d_in[5];
    const int*   leaf_masks  = (const int*)d_in[6];
    const float* Wl1 = (const float*)d_in[7];
    const float* bl1 = (const float*)d_in[8];
    const float* Wl2 = (const float*)d_in[9];
    const float* bl2 = (const float*)d_in[10];
    const float* Wm1 = (const float*)d_in[11];
    const float* bm1 = (const float*)d_in[12];
    const float* Wm2 = (const float*)d_in[13];
    const float* bm2 = (const float*)d_in[14];
    const float* depth_emb = (const float*)d_in[15];
    const float* shape_emb = (const float*)d_in[16];
    float* out = (float*)d_out;

    // ws layout: f32 region first, then bf16 (ushort) region; all 16B-aligned
    float* part   = (float*)d_ws;                 // 4*832*768 f32
    float* cntbuf = part + 4*832*768;             // 4*832 f32
    ushort* pooled  = (ushort*)(cntbuf + 4*832);  // 832*768 bf16
    ushort* hidden  = pooled + 832*768;           // 832*512
    ushort* noderep = hidden + 832*512;           // 832*512
    ushort* mhid    = noderep + 832*512;          // 3*64*512
    ushort* Tl1 = mhid + 3*64*512;                // 512*768
    ushort* Tl2 = Tl1 + 512*768;                  // 512*512
    ushort* Tm1 = Tl2 + 512*512;                  // 512*1024
    ushort* Tm2 = Tm1 + 512*1024;                 // 512*512

    pool_partial<<<832*4, 192, 0, stream>>>(leaf_states, leaf_masks, is_leaf, part, cntbuf);
    combine_transpose<<<832 + 1408, 256, 0, stream>>>(part, cntbuf, is_leaf, pooled,
                                                      Wl1, Wl2, Wm1, Wm2, Tl1, Tl2, Tm1, Tm2);

    // leaf MLP (all nodes; no-leaf nodes short-circuit / zero-fill)
    mfma_gemm<LEAF_G1, 768><<<dim3(8, 13), 256, 0, stream>>>(
        pooled, Tl1, bl1, hidden, is_leaf, active, depth, left, right,
        depth_emb, shape_emb, noderep, 0, 0, 0);
    mfma_gemm<LEAF_G2, 512><<<dim3(8, 13), 256, 0, stream>>>(
        hidden, Tl2, bl2, noderep, is_leaf, active, depth, left, right,
        depth_emb, shape_emb, noderep, 0, 0, 0);

    // merge level 1: nodes {3,4,5}
    mfma_gemm<MERGE_G1, 1024><<<dim3(8, 3), 256, 0, stream>>>(
        nullptr, Tm1, bm1, mhid, is_leaf, active, depth, left, right,
        depth_emb, shape_emb, noderep, 3, 4, 5);
    mfma_gemm<MERGE_G2, 512><<<dim3(8, 3), 256, 0, stream>>>(
        mhid, Tm2, bm2, noderep, is_leaf, active, depth, left, right,
        depth_emb, shape_emb, noderep, 3, 4, 5);

    // merge level 2: nodes {1,2}
    mfma_gemm<MERGE_G1, 1024><<<dim3(8, 2), 256, 0, stream>>>(
        nullptr, Tm1, bm1, mhid, is_leaf, active, depth, left, right,
        depth_emb, shape_emb, noderep, 1, 2, 0);
    mfma_gemm<MERGE_G2, 512><<<dim3(8, 2), 256, 0, stream>>>(
        mhid, Tm2, bm2, noderep, is_leaf, active, depth, left, right,
        depth_emb, shape_emb, noderep, 1, 2, 0);

    // merge level 3: node {0} -> fused hash + shape_emb + f32 output
    mfma_gemm<MERGE_G1, 1024><<<dim3(8, 1), 256, 0, stream>>>(
        nullptr, Tm1, bm1, mhid, is_leaf, active, depth, left, right,
        depth_emb, shape_emb, noderep, 0, 0, 0);
    mfma_gemm<FINAL_G2, 512><<<dim3(8, 1), 256, 0, stream>>>(
        mhid, Tm2, bm2, out, is_leaf, active, depth, left, right,
        depth_emb, shape_emb, noderep, 0, 0, 0);
}

// Round 8
// 99.014 us; speedup vs baseline: 3.1530x; 1.0377x over previous
//
#include <hip/hip_runtime.h>
#include <hip/hip_bf16.h>
#include <math.h>

#define NN 13
#define SS 128
#define HH 768
#define DD 512

typedef __attribute__((ext_vector_type(8))) short bf16x8;
typedef __attribute__((ext_vector_type(4))) float f32x4;

__device__ __forceinline__ float gelu_f(float x) {
    return 0.5f * x * (1.0f + erff(x * 0.7071067811865475f));
}
__device__ __forceinline__ ushort f2b(float v) {
    __hip_bfloat16 h = __float2bfloat16(v);
    return *reinterpret_cast<ushort*>(&h);
}
__device__ __forceinline__ float b2f(ushort u) {
    __hip_bfloat16 h = *reinterpret_cast<__hip_bfloat16*>(&u);
    return __bfloat162float(h);
}

__device__ __forceinline__ int shape_hash(const int* __restrict__ active,
                                          const int* __restrict__ is_leaf, int b) {
    unsigned long long acc = 0ull, w = 1ull;
    for (int i = 0; i < NN; ++i) {
        unsigned long long p = (unsigned long long)(active[b*NN + i] * 2 + is_leaf[b*NN + i]);
        acc += p * w;
        w *= 31ull;
    }
    long long h = (long long)acc;
    if (h < 0) h = -h;
    return (int)(h % 256);
}

// ---------- fused: direct pool (bx<832) + weight transpose (bx>=832) ----------
// Pool block: one unit R = n*64+b; 192 active float4 lanes sweep all 128 s rows,
// divide by mask count, write pooled bf16 directly (no partials round-trip).
__global__ __launch_bounds__(256)
void pool_transpose(const float* __restrict__ ls, const int* __restrict__ masks,
                    const int* __restrict__ is_leaf, ushort* __restrict__ pooled,
                    const float* __restrict__ Wl1, const float* __restrict__ Wl2,
                    const float* __restrict__ Wm1, const float* __restrict__ Wm2,
                    ushort* __restrict__ Tl1, ushort* __restrict__ Tl2,
                    ushort* __restrict__ Tm1, ushort* __restrict__ Tm2)
{
    int bx = blockIdx.x;
    int t = threadIdx.x;
    if (bx < 832) {
        int u = bx;
        int n = u >> 6, b = u & 63;
        ushort4* dst = (ushort4*)(pooled + (size_t)u * HH);
        if (!is_leaf[b*NN + n]) {              // uniform branch: whole block exits
            if (t < 192) { ushort4 z = {0,0,0,0}; dst[t] = z; }
            return;
        }
        __shared__ float lsm[SS];
        if (t < SS) lsm[t] = (float)masks[(b*NN + n)*SS + t];
        __syncthreads();
        if (t >= 192) return;
        const float4* src = (const float4*)(ls + (size_t)(b*NN + n) * SS * HH);
        float4 a = {0.f, 0.f, 0.f, 0.f};
        float cnt = 0.f;
        #pragma unroll 8
        for (int s = 0; s < SS; ++s) {
            float m = lsm[s];
            float4 v = src[s * (HH/4) + t];
            a.x += m * v.x; a.y += m * v.y; a.z += m * v.z; a.w += m * v.w;
            cnt += m;
        }
        float inv = 1.f / fmaxf(cnt, 1.f);
        ushort4 o = { f2b(a.x*inv), f2b(a.y*inv), f2b(a.z*inv), f2b(a.w*inv) };
        dst[t] = o;
        return;
    }
    // transpose part: W[K][512] f32 -> WT[512][K] bf16
    int tb = bx - 832;
    const float* W; ushort* T; int K, tile;
    if (tb < 384)       { W = Wl1; T = Tl1; K = 768;  tile = tb; }
    else if (tb < 640)  { W = Wl2; T = Tl2; K = 512;  tile = tb - 384; }
    else if (tb < 1152) { W = Wm1; T = Tm1; K = 1024; tile = tb - 640; }
    else                { W = Wm2; T = Tm2; K = 512;  tile = tb - 1152; }
    int tk = tile >> 4, tj = tile & 15;
    __shared__ float lds[32][33];
    int r = t >> 3, c0 = (t & 7) * 4;
    const float4 v = *(const float4*)(W + (size_t)(tk*32 + r)*DD + tj*32 + c0);
    lds[r][c0+0] = v.x; lds[r][c0+1] = v.y; lds[r][c0+2] = v.z; lds[r][c0+3] = v.w;
    __syncthreads();
    ushort* dst = T + (size_t)(tj*32 + r)*K + tk*32 + c0;
    dst[0] = f2b(lds[c0+0][r]); dst[1] = f2b(lds[c0+1][r]);
    dst[2] = f2b(lds[c0+2][r]); dst[3] = f2b(lds[c0+3][r]);
}

enum { LEAF_G1 = 0, LEAF_G2 = 1, MERGE_G1 = 2, MERGE_G2 = 3, FINAL_G2 = 4 };

// MFMA GEMM: round-3 structure (BK=32, double-buffered LDS, 1 sync/iter) with a
// 2-deep prefetch pipeline: two NAMED register sets (compile-time slots), loop
// unrolled x2 so the global load consumed by each LDS store was issued one full
// iteration earlier (hides L2 latency instead of exposing it at the store).
template<int MODE, int KT>
__global__ __launch_bounds__(256)
void mfma_gemm(const ushort* __restrict__ Asrc, const ushort* __restrict__ WT,
               const float* __restrict__ bias, void* __restrict__ CoutV,
               const int* __restrict__ is_leaf, const int* __restrict__ active,
               const int* __restrict__ depth, const int* __restrict__ left,
               const int* __restrict__ right,
               const float* __restrict__ depth_emb, const float* __restrict__ shape_emb,
               const ushort* __restrict__ noderep,
               int n0, int n1, int n2)
{
    constexpr int NITER = KT / 32;          // 16, 24, or 32 (always even)
    __shared__ ushort a_lds[2][64*40];
    __shared__ ushort b_lds[2][64*40];

    const int t = threadIdx.x;
    const int lane = t & 63, wv = t >> 6;
    const int j0 = blockIdx.x * 64;
    const int by = blockIdx.y;
    const int lrow = lane & 15, lhi = lane >> 4;

    int node, lc = 0, rc = 0;
    if (MODE == LEAF_G1 || MODE == LEAF_G2) {
        node = by;
        bool anyleaf = __any(is_leaf[lane*NN + node] != 0);
        if (!anyleaf) {
            if (MODE == LEAF_G2) {           // zero-init this noderep column
                ushort* dst = (ushort*)CoutV + (size_t)(node*64)*DD;
                #pragma unroll
                for (int c = 0; c < 4; ++c) {
                    int jc = j0 + c*16 + lrow;
                    #pragma unroll
                    for (int reg = 0; reg < 4; ++reg) {
                        int rw = wv*16 + lhi*4 + reg;
                        dst[(size_t)rw*DD + jc] = 0;
                    }
                }
            }
            return;
        }
    } else {
        node = (by == 0) ? n0 : ((by == 1) ? n1 : n2);
        lc = left[node]; rc = right[node];
    }

    const int AK = (MODE == LEAF_G1) ? HH : DD;
    const int rowbase = (MODE == LEAF_G1 || MODE == LEAF_G2) ? node*64
                       : (MODE == MERGE_G1) ? 0 : by*64;

    const int sr = t >> 2, skg = t & 3;
    f32x4 acc[4];
    #pragma unroll
    for (int c = 0; c < 4; ++c) acc[c] = (f32x4){0.f, 0.f, 0.f, 0.f};

    auto addrA = [&](int kt) -> const ushort* {
        int k0 = kt*32 + skg*8;
        if (MODE == MERGE_G1) {
            return (k0 < DD) ? noderep + (size_t)(lc*64 + sr)*DD + k0
                             : noderep + (size_t)(rc*64 + sr)*DD + (k0 - DD);
        }
        return Asrc + (size_t)(rowbase + sr)*AK + k0;
    };
    auto addrB = [&](int kt) -> const ushort* {
        return WT + (size_t)(j0 + sr)*KT + kt*32 + skg*8;
    };

    uint4 aR0, bR0, aR1, bR1;                        // two named prefetch sets
    auto load0 = [&](int kt) { aR0 = *(const uint4*)addrA(kt); bR0 = *(const uint4*)addrB(kt); };
    auto load1 = [&](int kt) { aR1 = *(const uint4*)addrA(kt); bR1 = *(const uint4*)addrB(kt); };
    auto store0 = [&](int buf) {
        *(uint4*)&a_lds[buf][sr*40 + skg*8] = aR0;
        *(uint4*)&b_lds[buf][sr*40 + skg*8] = bR0;
    };
    auto store1 = [&](int buf) {
        *(uint4*)&a_lds[buf][sr*40 + skg*8] = aR1;
        *(uint4*)&b_lds[buf][sr*40 + skg*8] = bR1;
    };
    auto computeOn = [&](const ushort* aL, const ushort* bL) {
        bf16x8 af = *(const bf16x8*)&aL[(wv*16 + lrow)*40 + lhi*8];
        #pragma unroll
        for (int c = 0; c < 4; ++c) {
            bf16x8 bfr = *(const bf16x8*)&bL[(c*16 + lrow)*40 + lhi*8];
            acc[c] = __builtin_amdgcn_mfma_f32_16x16x32_bf16(af, bfr, acc[c], 0, 0, 0);
        }
    };

    // prologue: kt0 -> buf0 (latency exposed once); prefetch kt1 -> set1
    load0(0);
    store0(0);
    if (NITER > 1) load1(1);
    __syncthreads();

    for (int kt = 0; kt < NITER; kt += 2) {
        // even half: compute buf0 (kt), prefetch kt+2 -> set0, stage kt+1 -> buf1
        computeOn(a_lds[0], b_lds[0]);
        if (kt + 2 < NITER) load0(kt + 2);
        store1(1);
        __syncthreads();
        // odd half: compute buf1 (kt+1), prefetch kt+3 -> set1, stage kt+2 -> buf0
        computeOn(a_lds[1], b_lds[1]);
        if (kt + 3 < NITER) load1(kt + 3);
        if (kt + 2 < NITER) store0(0);
        __syncthreads();
    }

    // ---------------- epilogue ----------------
    if (MODE == LEAF_G1) {
        ushort* H = (ushort*)CoutV + (size_t)(node*64)*DD;
        #pragma unroll
        for (int c = 0; c < 4; ++c) {
            int jc = j0 + c*16 + lrow;
            float bj = bias[jc];
            #pragma unroll
            for (int reg = 0; reg < 4; ++reg) {
                int rw = wv*16 + lhi*4 + reg;
                H[(size_t)rw*DD + jc] = f2b(gelu_f(acc[c][reg] + bj));
            }
        }
    } else if (MODE == LEAF_G2) {
        int dp = depth[node];
        const float* de = depth_emb + (size_t)dp*DD;
        bool lf[4];
        #pragma unroll
        for (int reg = 0; reg < 4; ++reg)
            lf[reg] = is_leaf[(wv*16 + lhi*4 + reg)*NN + node] != 0;
        ushort* dst = (ushort*)CoutV + (size_t)(node*64)*DD;
        #pragma unroll
        for (int c = 0; c < 4; ++c) {
            int jc = j0 + c*16 + lrow;
            float bj = bias[jc] + de[jc];
            #pragma unroll
            for (int reg = 0; reg < 4; ++reg) {
                int rw = wv*16 + lhi*4 + reg;
                dst[(size_t)rw*DD + jc] = f2b(lf[reg] ? (acc[c][reg] + bj) : 0.f);
            }
        }
    } else if (MODE == MERGE_G1) {
        ushort* Mh = (ushort*)CoutV + (size_t)(by*64)*DD;
        #pragma unroll
        for (int c = 0; c < 4; ++c) {
            int jc = j0 + c*16 + lrow;
            float bj = bias[jc];
            #pragma unroll
            for (int reg = 0; reg < 4; ++reg) {
                int rw = wv*16 + lhi*4 + reg;
                Mh[(size_t)rw*DD + jc] = f2b(gelu_f(acc[c][reg] + bj));
            }
        }
    } else {
        int dp = depth[node];
        const float* de = depth_emb + (size_t)dp*DD;
        bool anyInt = __any(active[lane*NN + node] && !is_leaf[lane*NN + node]);
        bool iv[4];
        #pragma unroll
        for (int reg = 0; reg < 4; ++reg) {
            int rw = wv*16 + lhi*4 + reg;
            iv[reg] = active[rw*NN + node] && !is_leaf[rw*NN + node];
        }
        if (MODE == MERGE_G2) {
            if (!anyInt) return;             // keep existing noderep column
            ushort* dst = (ushort*)CoutV + (size_t)(node*64)*DD;
            #pragma unroll
            for (int c = 0; c < 4; ++c) {
                int jc = j0 + c*16 + lrow;
                float bj = bias[jc] + de[jc];
                #pragma unroll
                for (int reg = 0; reg < 4; ++reg) {
                    int rw = wv*16 + lhi*4 + reg;
                    dst[(size_t)rw*DD + jc] = f2b(iv[reg] ? (acc[c][reg] + bj) : 0.f);
                }
            }
        } else {  // FINAL_G2 -> f32 out + shape_emb
            float* out = (float*)CoutV;
            int hh[4];
            #pragma unroll
            for (int reg = 0; reg < 4; ++reg)
                hh[reg] = shape_hash(active, is_leaf, wv*16 + lhi*4 + reg);
            #pragma unroll
            for (int c = 0; c < 4; ++c) {
                int jc = j0 + c*16 + lrow;
                float bj = bias[jc] + de[jc];
                #pragma unroll
                for (int reg = 0; reg < 4; ++reg) {
                    int rw = wv*16 + lhi*4 + reg;
                    float base = anyInt ? (iv[reg] ? (acc[c][reg] + bj) : 0.f)
                                        : b2f(noderep[(size_t)(node*64 + rw)*DD + jc]);
                    out[(size_t)rw*DD + jc] = base + shape_emb[(size_t)hh[reg]*DD + jc];
                }
            }
        }
    }
}

extern "C" void kernel_launch(void* const* d_in, const int* in_sizes, int n_in,
                              void* d_out, int out_size, void* d_ws, size_t ws_size,
                              hipStream_t stream)
{
    const int*   is_leaf     = (const int*)d_in[0];
    const int*   active      = (const int*)d_in[1];
    const int*   depth       = (const int*)d_in[2];
    const int*   left        = (const int*)d_in[3];
    const int*   right       = (const int*)d_in[4];
    const float* leaf_states = (const float*)d_in[5];
    const int*   leaf_masks  = (const int*)d_in[6];
    const float* Wl1 = (const float*)d_in[7];
    const float* bl1 = (const float*)d_in[8];
    const float* Wl2 = (const float*)d_in[9];
    const float* bl2 = (const float*)d_in[10];
    const float* Wm1 = (const float*)d_in[11];
    const float* bm1 = (const float*)d_in[12];
    const float* Wm2 = (const float*)d_in[13];
    const float* bm2 = (const float*)d_in[14];
    const float* depth_emb = (const float*)d_in[15];
    const float* shape_emb = (const float*)d_in[16];
    float* out = (float*)d_out;

    // ws layout (bf16/ushort region; all 16B-aligned)
    ushort* pooled  = (ushort*)d_ws;              // 832*768 bf16
    ushort* hidden  = pooled + 832*768;           // 832*512
    ushort* noderep = hidden + 832*512;           // 832*512
    ushort* mhid    = noderep + 832*512;          // 3*64*512
    ushort* Tl1 = mhid + 3*64*512;                // 512*768
    ushort* Tl2 = Tl1 + 512*768;                  // 512*512
    ushort* Tm1 = Tl2 + 512*512;                  // 512*1024
    ushort* Tm2 = Tm1 + 512*1024;                 // 512*512

    pool_transpose<<<832 + 1408, 256, 0, stream>>>(leaf_states, leaf_masks, is_leaf, pooled,
                                                   Wl1, Wl2, Wm1, Wm2, Tl1, Tl2, Tm1, Tm2);

    // leaf MLP (all nodes; no-leaf nodes short-circuit / zero-fill)
    mfma_gemm<LEAF_G1, 768><<<dim3(8, 13), 256, 0, stream>>>(
        pooled, Tl1, bl1, hidden, is_leaf, active, depth, left, right,
        depth_emb, shape_emb, noderep, 0, 0, 0);
    mfma_gemm<LEAF_G2, 512><<<dim3(8, 13), 256, 0, stream>>>(
        hidden, Tl2, bl2, noderep, is_leaf, active, depth, left, right,
        depth_emb, shape_emb, noderep, 0, 0, 0);

    // merge level 1: nodes {3,4,5}
    mfma_gemm<MERGE_G1, 1024><<<dim3(8, 3), 256, 0, stream>>>(
        nullptr, Tm1, bm1, mhid, is_leaf, active, depth, left, right,
        depth_emb, shape_emb, noderep, 3, 4, 5);
    mfma_gemm<MERGE_G2, 512><<<dim3(8, 3), 256, 0, stream>>>(
        mhid, Tm2, bm2, noderep, is_leaf, active, depth, left, right,
        depth_emb, shape_emb, noderep, 3, 4, 5);

    // merge level 2: nodes {1,2}
    mfma_gemm<MERGE_G1, 1024><<<dim3(8, 2), 256, 0, stream>>>(
        nullptr, Tm1, bm1, mhid, is_leaf, active, depth, left, right,
        depth_emb, shape_emb, noderep, 1, 2, 0);
    mfma_gemm<MERGE_G2, 512><<<dim3(8, 2), 256, 0, stream>>>(
        mhid, Tm2, bm2, noderep, is_leaf, active, depth, left, right,
        depth_emb, shape_emb, noderep, 1, 2, 0);

    // merge level 3: node {0} -> fused hash + shape_emb + f32 output
    mfma_gemm<MERGE_G1, 1024><<<dim3(8, 1), 256, 0, stream>>>(
        nullptr, Tm1, bm1, mhid, is_leaf, active, depth, left, right,
        depth_emb, shape_emb, noderep, 0, 0, 0);
    mfma_gemm<FINAL_G2, 512><<<dim3(8, 1), 256, 0, stream>>>(
        mhid, Tm2, bm2, out, is_leaf, active, depth, left, right,
        depth_emb, shape_emb, noderep, 0, 0, 0);
}

// Round 9
// 98.835 us; speedup vs baseline: 3.1587x; 1.0018x over previous
//
#include <hip/hip_runtime.h>
#include <hip/hip_bf16.h>
#include <math.h>

#define NN 13
#define SS 128
#define HH 768
#define DD 512

typedef __attribute__((ext_vector_type(8))) short bf16x8;
typedef __attribute__((ext_vector_type(4))) float f32x4;

__device__ __forceinline__ float gelu_f(float x) {
    return 0.5f * x * (1.0f + erff(x * 0.7071067811865475f));
}
__device__ __forceinline__ ushort f2b(float v) {
    __hip_bfloat16 h = __float2bfloat16(v);
    return *reinterpret_cast<ushort*>(&h);
}
__device__ __forceinline__ float b2f(ushort u) {
    __hip_bfloat16 h = *reinterpret_cast<__hip_bfloat16*>(&u);
    return __bfloat162float(h);
}

__device__ __forceinline__ int shape_hash(const int* __restrict__ active,
                                          const int* __restrict__ is_leaf, int b) {
    unsigned long long acc = 0ull, w = 1ull;
    for (int i = 0; i < NN; ++i) {
        unsigned long long p = (unsigned long long)(active[b*NN + i] * 2 + is_leaf[b*NN + i]);
        acc += p * w;
        w *= 31ull;
    }
    long long h = (long long)acc;
    if (h < 0) h = -h;
    return (int)(h % 256);
}

// ---------- fused: column-split pool (bx < 2496) + weight transpose ----------
// Pool block: (unit u, col-third q); 64 lanes, lane owns float4-column q*64+t,
// sweeps all 128 s rows. 1344 active blocks -> ~5.25/CU (balance), no partials.
__global__ __launch_bounds__(256)
void pool_transpose(const float* __restrict__ ls, const int* __restrict__ masks,
                    const int* __restrict__ is_leaf, ushort* __restrict__ pooled,
                    const float* __restrict__ Wl1, const float* __restrict__ Wl2,
                    const float* __restrict__ Wm1, const float* __restrict__ Wm2,
                    ushort* __restrict__ Tl1, ushort* __restrict__ Tl2,
                    ushort* __restrict__ Tm1, ushort* __restrict__ Tm2)
{
    int bx = blockIdx.x;
    int t = threadIdx.x;
    if (bx < 2496) {
        if (t >= 64) return;                 // 1-wave pool blocks
        int u = bx / 3, q = bx - u*3;
        int n = u >> 6, b = u & 63;
        int c = q*64 + t;                    // float4 column 0..191
        ushort4* dst = (ushort4*)(pooled + (size_t)u * HH);
        if (!is_leaf[b*NN + n]) {            // uniform: zero-fill and exit
            ushort4 z = {0,0,0,0};
            dst[c] = z;
            return;
        }
        __shared__ float lsm[SS];
        const int* mk = masks + (b*NN + n)*SS;
        lsm[t] = (float)mk[t];
        lsm[64 + t] = (float)mk[64 + t];
        __syncthreads();
        const float4* src = (const float4*)(ls + (size_t)(b*NN + n) * SS * HH);
        float4 a = {0.f, 0.f, 0.f, 0.f};
        float cnt = 0.f;
        #pragma unroll 8
        for (int s = 0; s < SS; ++s) {
            float m = lsm[s];
            float4 v = src[(size_t)s * (HH/4) + c];
            a.x += m * v.x; a.y += m * v.y; a.z += m * v.z; a.w += m * v.w;
            cnt += m;
        }
        float inv = 1.f / fmaxf(cnt, 1.f);
        ushort4 o = { f2b(a.x*inv), f2b(a.y*inv), f2b(a.z*inv), f2b(a.w*inv) };
        dst[c] = o;
        return;
    }
    // transpose part: W[K][512] f32 -> WT[512][K] bf16
    int tb = bx - 2496;
    const float* W; ushort* T; int K, tile;
    if (tb < 384)       { W = Wl1; T = Tl1; K = 768;  tile = tb; }
    else if (tb < 640)  { W = Wl2; T = Tl2; K = 512;  tile = tb - 384; }
    else if (tb < 1152) { W = Wm1; T = Tm1; K = 1024; tile = tb - 640; }
    else                { W = Wm2; T = Tm2; K = 512;  tile = tb - 1152; }
    int tk = tile >> 4, tj = tile & 15;
    __shared__ float lds[32][33];
    int r = t >> 3, c0 = (t & 7) * 4;
    const float4 v = *(const float4*)(W + (size_t)(tk*32 + r)*DD + tj*32 + c0);
    lds[r][c0+0] = v.x; lds[r][c0+1] = v.y; lds[r][c0+2] = v.z; lds[r][c0+3] = v.w;
    __syncthreads();
    ushort* dst = T + (size_t)(tj*32 + r)*K + tk*32 + c0;
    dst[0] = f2b(lds[c0+0][r]); dst[1] = f2b(lds[c0+1][r]);
    dst[2] = f2b(lds[c0+2][r]); dst[3] = f2b(lds[c0+3][r]);
}

enum { LEAF_G1 = 0, LEAF_G2 = 1, MERGE_G1 = 2, MERGE_G2 = 3, FINAL_G2 = 4 };

// MFMA GEMM: round-3 structure (BK=32, double-buffered LDS, 1 sync/iter) with a
// 2-deep prefetch pipeline: two NAMED register sets (compile-time slots), loop
// unrolled x2 so the global load consumed by each LDS store was issued one full
// iteration earlier (hides L2 latency instead of exposing it at the store).
template<int MODE, int KT>
__global__ __launch_bounds__(256)
void mfma_gemm(const ushort* __restrict__ Asrc, const ushort* __restrict__ WT,
               const float* __restrict__ bias, void* __restrict__ CoutV,
               const int* __restrict__ is_leaf, const int* __restrict__ active,
               const int* __restrict__ depth, const int* __restrict__ left,
               const int* __restrict__ right,
               const float* __restrict__ depth_emb, const float* __restrict__ shape_emb,
               const ushort* __restrict__ noderep,
               int n0, int n1, int n2)
{
    constexpr int NITER = KT / 32;          // 16, 24, or 32 (always even)
    __shared__ ushort a_lds[2][64*40];
    __shared__ ushort b_lds[2][64*40];

    const int t = threadIdx.x;
    const int lane = t & 63, wv = t >> 6;
    const int j0 = blockIdx.x * 64;
    const int by = blockIdx.y;
    const int lrow = lane & 15, lhi = lane >> 4;

    int node, lc = 0, rc = 0;
    if (MODE == LEAF_G1 || MODE == LEAF_G2) {
        node = by;
        bool anyleaf = __any(is_leaf[lane*NN + node] != 0);
        if (!anyleaf) {
            if (MODE == LEAF_G2) {           // zero-init this noderep column
                ushort* dst = (ushort*)CoutV + (size_t)(node*64)*DD;
                #pragma unroll
                for (int c = 0; c < 4; ++c) {
                    int jc = j0 + c*16 + lrow;
                    #pragma unroll
                    for (int reg = 0; reg < 4; ++reg) {
                        int rw = wv*16 + lhi*4 + reg;
                        dst[(size_t)rw*DD + jc] = 0;
                    }
                }
            }
            return;
        }
    } else {
        node = (by == 0) ? n0 : ((by == 1) ? n1 : n2);
        lc = left[node]; rc = right[node];
    }

    const int AK = (MODE == LEAF_G1) ? HH : DD;
    const int rowbase = (MODE == LEAF_G1 || MODE == LEAF_G2) ? node*64
                       : (MODE == MERGE_G1) ? 0 : by*64;

    const int sr = t >> 2, skg = t & 3;
    f32x4 acc[4];
    #pragma unroll
    for (int c = 0; c < 4; ++c) acc[c] = (f32x4){0.f, 0.f, 0.f, 0.f};

    auto addrA = [&](int kt) -> const ushort* {
        int k0 = kt*32 + skg*8;
        if (MODE == MERGE_G1) {
            return (k0 < DD) ? noderep + (size_t)(lc*64 + sr)*DD + k0
                             : noderep + (size_t)(rc*64 + sr)*DD + (k0 - DD);
        }
        return Asrc + (size_t)(rowbase + sr)*AK + k0;
    };
    auto addrB = [&](int kt) -> const ushort* {
        return WT + (size_t)(j0 + sr)*KT + kt*32 + skg*8;
    };

    uint4 aR0, bR0, aR1, bR1;                        // two named prefetch sets
    auto load0 = [&](int kt) { aR0 = *(const uint4*)addrA(kt); bR0 = *(const uint4*)addrB(kt); };
    auto load1 = [&](int kt) { aR1 = *(const uint4*)addrA(kt); bR1 = *(const uint4*)addrB(kt); };
    auto store0 = [&](int buf) {
        *(uint4*)&a_lds[buf][sr*40 + skg*8] = aR0;
        *(uint4*)&b_lds[buf][sr*40 + skg*8] = bR0;
    };
    auto store1 = [&](int buf) {
        *(uint4*)&a_lds[buf][sr*40 + skg*8] = aR1;
        *(uint4*)&b_lds[buf][sr*40 + skg*8] = bR1;
    };
    auto computeOn = [&](const ushort* aL, const ushort* bL) {
        bf16x8 af = *(const bf16x8*)&aL[(wv*16 + lrow)*40 + lhi*8];
        #pragma unroll
        for (int c = 0; c < 4; ++c) {
            bf16x8 bfr = *(const bf16x8*)&bL[(c*16 + lrow)*40 + lhi*8];
            acc[c] = __builtin_amdgcn_mfma_f32_16x16x32_bf16(af, bfr, acc[c], 0, 0, 0);
        }
    };

    // prologue: kt0 -> buf0 (latency exposed once); prefetch kt1 -> set1
    load0(0);
    store0(0);
    if (NITER > 1) load1(1);
    __syncthreads();

    for (int kt = 0; kt < NITER; kt += 2) {
        // even half: compute buf0 (kt), prefetch kt+2 -> set0, stage kt+1 -> buf1
        computeOn(a_lds[0], b_lds[0]);
        if (kt + 2 < NITER) load0(kt + 2);
        store1(1);
        __syncthreads();
        // odd half: compute buf1 (kt+1), prefetch kt+3 -> set1, stage kt+2 -> buf0
        computeOn(a_lds[1], b_lds[1]);
        if (kt + 3 < NITER) load1(kt + 3);
        if (kt + 2 < NITER) store0(0);
        __syncthreads();
    }

    // ---------------- epilogue ----------------
    if (MODE == LEAF_G1) {
        ushort* H = (ushort*)CoutV + (size_t)(node*64)*DD;
        #pragma unroll
        for (int c = 0; c < 4; ++c) {
            int jc = j0 + c*16 + lrow;
            float bj = bias[jc];
            #pragma unroll
            for (int reg = 0; reg < 4; ++reg) {
                int rw = wv*16 + lhi*4 + reg;
                H[(size_t)rw*DD + jc] = f2b(gelu_f(acc[c][reg] + bj));
            }
        }
    } else if (MODE == LEAF_G2) {
        int dp = depth[node];
        const float* de = depth_emb + (size_t)dp*DD;
        bool lf[4];
        #pragma unroll
        for (int reg = 0; reg < 4; ++reg)
            lf[reg] = is_leaf[(wv*16 + lhi*4 + reg)*NN + node] != 0;
        ushort* dst = (ushort*)CoutV + (size_t)(node*64)*DD;
        #pragma unroll
        for (int c = 0; c < 4; ++c) {
            int jc = j0 + c*16 + lrow;
            float bj = bias[jc] + de[jc];
            #pragma unroll
            for (int reg = 0; reg < 4; ++reg) {
                int rw = wv*16 + lhi*4 + reg;
                dst[(size_t)rw*DD + jc] = f2b(lf[reg] ? (acc[c][reg] + bj) : 0.f);
            }
        }
    } else if (MODE == MERGE_G1) {
        ushort* Mh = (ushort*)CoutV + (size_t)(by*64)*DD;
        #pragma unroll
        for (int c = 0; c < 4; ++c) {
            int jc = j0 + c*16 + lrow;
            float bj = bias[jc];
            #pragma unroll
            for (int reg = 0; reg < 4; ++reg) {
                int rw = wv*16 + lhi*4 + reg;
                Mh[(size_t)rw*DD + jc] = f2b(gelu_f(acc[c][reg] + bj));
            }
        }
    } else {
        int dp = depth[node];
        const float* de = depth_emb + (size_t)dp*DD;
        bool anyInt = __any(active[lane*NN + node] && !is_leaf[lane*NN + node]);
        bool iv[4];
        #pragma unroll
        for (int reg = 0; reg < 4; ++reg) {
            int rw = wv*16 + lhi*4 + reg;
            iv[reg] = active[rw*NN + node] && !is_leaf[rw*NN + node];
        }
        if (MODE == MERGE_G2) {
            if (!anyInt) return;             // keep existing noderep column
            ushort* dst = (ushort*)CoutV + (size_t)(node*64)*DD;
            #pragma unroll
            for (int c = 0; c < 4; ++c) {
                int jc = j0 + c*16 + lrow;
                float bj = bias[jc] + de[jc];
                #pragma unroll
                for (int reg = 0; reg < 4; ++reg) {
                    int rw = wv*16 + lhi*4 + reg;
                    dst[(size_t)rw*DD + jc] = f2b(iv[reg] ? (acc[c][reg] + bj) : 0.f);
                }
            }
        } else {  // FINAL_G2 -> f32 out + shape_emb
            float* out = (float*)CoutV;
            int hh[4];
            #pragma unroll
            for (int reg = 0; reg < 4; ++reg)
                hh[reg] = shape_hash(active, is_leaf, wv*16 + lhi*4 + reg);
            #pragma unroll
            for (int c = 0; c < 4; ++c) {
                int jc = j0 + c*16 + lrow;
                float bj = bias[jc] + de[jc];
                #pragma unroll
                for (int reg = 0; reg < 4; ++reg) {
                    int rw = wv*16 + lhi*4 + reg;
                    float base = anyInt ? (iv[reg] ? (acc[c][reg] + bj) : 0.f)
                                        : b2f(noderep[(size_t)(node*64 + rw)*DD + jc]);
                    out[(size_t)rw*DD + jc] = base + shape_emb[(size_t)hh[reg]*DD + jc];
                }
            }
        }
    }
}

extern "C" void kernel_launch(void* const* d_in, const int* in_sizes, int n_in,
                              void* d_out, int out_size, void* d_ws, size_t ws_size,
                              hipStream_t stream)
{
    const int*   is_leaf     = (const int*)d_in[0];
    const int*   active      = (const int*)d_in[1];
    const int*   depth       = (const int*)d_in[2];
    const int*   left        = (const int*)d_in[3];
    const int*   right       = (const int*)d_in[4];
    const float* leaf_states = (const float*)d_in[5];
    const int*   leaf_masks  = (const int*)d_in[6];
    const float* Wl1 = (const float*)d_in[7];
    const float* bl1 = (const float*)d_in[8];
    const float* Wl2 = (const float*)d_in[9];
    const float* bl2 = (const float*)d_in[10];
    const float* Wm1 = (const float*)d_in[11];
    const float* bm1 = (const float*)d_in[12];
    const float* Wm2 = (const float*)d_in[13];
    const float* bm2 = (const float*)d_in[14];
    const float* depth_emb = (const float*)d_in[15];
    const float* shape_emb = (const float*)d_in[16];
    float* out = (float*)d_out;

    // ws layout (bf16/ushort region; all 16B-aligned)
    ushort* pooled  = (ushort*)d_ws;              // 832*768 bf16
    ushort* hidden  = pooled + 832*768;           // 832*512
    ushort* noderep = hidden + 832*512;           // 832*512
    ushort* mhid    = noderep + 832*512;          // 3*64*512
    ushort* Tl1 = mhid + 3*64*512;                // 512*768
    ushort* Tl2 = Tl1 + 512*768;                  // 512*512
    ushort* Tm1 = Tl2 + 512*512;                  // 512*1024
    ushort* Tm2 = Tm1 + 512*1024;                 // 512*512

    pool_transpose<<<2496 + 1408, 256, 0, stream>>>(leaf_states, leaf_masks, is_leaf, pooled,
                                                    Wl1, Wl2, Wm1, Wm2, Tl1, Tl2, Tm1, Tm2);

    // leaf MLP (all nodes; no-leaf nodes short-circuit / zero-fill)
    mfma_gemm<LEAF_G1, 768><<<dim3(8, 13), 256, 0, stream>>>(
        pooled, Tl1, bl1, hidden, is_leaf, active, depth, left, right,
        depth_emb, shape_emb, noderep, 0, 0, 0);
    mfma_gemm<LEAF_G2, 512><<<dim3(8, 13), 256, 0, stream>>>(
        hidden, Tl2, bl2, noderep, is_leaf, active, depth, left, right,
        depth_emb, shape_emb, noderep, 0, 0, 0);

    // merge level 1: nodes {3,4,5}
    mfma_gemm<MERGE_G1, 1024><<<dim3(8, 3), 256, 0, stream>>>(
        nullptr, Tm1, bm1, mhid, is_leaf, active, depth, left, right,
        depth_emb, shape_emb, noderep, 3, 4, 5);
    mfma_gemm<MERGE_G2, 512><<<dim3(8, 3), 256, 0, stream>>>(
        mhid, Tm2, bm2, noderep, is_leaf, active, depth, left, right,
        depth_emb, shape_emb, noderep, 3, 4, 5);

    // merge level 2: nodes {1,2}
    mfma_gemm<MERGE_G1, 1024><<<dim3(8, 2), 256, 0, stream>>>(
        nullptr, Tm1, bm1, mhid, is_leaf, active, depth, left, right,
        depth_emb, shape_emb, noderep, 1, 2, 0);
    mfma_gemm<MERGE_G2, 512><<<dim3(8, 2), 256, 0, stream>>>(
        mhid, Tm2, bm2, noderep, is_leaf, active, depth, left, right,
        depth_emb, shape_emb, noderep, 1, 2, 0);

    // merge level 3: node {0} -> fused hash + shape_emb + f32 output
    mfma_gemm<MERGE_G1, 1024><<<dim3(8, 1), 256, 0, stream>>>(
        nullptr, Tm1, bm1, mhid, is_leaf, active, depth, left, right,
        depth_emb, shape_emb, noderep, 0, 0, 0);
    mfma_gemm<FINAL_G2, 512><<<dim3(8, 1), 256, 0, stream>>>(
        mhid, Tm2, bm2, out, is_leaf, active, depth, left, right,
        depth_emb, shape_emb, noderep, 0, 0, 0);
}